// Round 13
// baseline (226.139 us; speedup 1.0000x reference)
//
#include <hip/hip_runtime.h>
#include <hip/hip_bf16.h>
#include <stdint.h>

// Problem constants
#define BB  2
#define CC  256
#define NN  8192
#define CIc 256
#define LOG2E 1.4426950408889634f

typedef __attribute__((ext_vector_type(4)))  float f32x4;
typedef __attribute__((ext_vector_type(16))) float f32x16;
typedef __attribute__((ext_vector_type(8)))  short s16x8;   // 8 bf16 = 4 VGPR
typedef __attribute__((ext_vector_type(4)))  short s16x4;
typedef __attribute__((ext_vector_type(4)))  int   i32x4;
typedef __attribute__((ext_vector_type(2)))  int   i32x2;

static __device__ __forceinline__ short f2bf(float f) {
    union { float f; unsigned u; } v; v.f = f;
    unsigned r = (v.u + 0x7FFFu + ((v.u >> 16) & 1u)) >> 16;   // RNE
    return (short)r;
}
static __device__ __forceinline__ float bf2f(short h) {
    union { unsigned u; float f; } v; v.u = ((unsigned)(unsigned short)h) << 16;
    return v.f;
}

// async global->LDS, 16B per lane, dest = lds_base + lane*16 (wave-uniform base)
static __device__ __forceinline__ void gload16(const void* g, void* l) {
    __builtin_amdgcn_global_load_lds(
        (const __attribute__((address_space(1))) unsigned int*)g,
        (__attribute__((address_space(3))) unsigned int*)l, 16, 0, 0);
}

// ---------------------------------------------------------------------------
// Kernel 0: pack the 4 weight matrices (theta, phi, g, w) f32[256][256] into
// bf16 MFMA-fragment order:  Wf[m][ot][ks][lane][8e] =
//   W[ot*16 + (lane&15)][ks*32 + (lane>>4)*8 + e]
// ---------------------------------------------------------------------------
__global__ __launch_bounds__(256) void pack_kernel(
    const float* __restrict__ tw, const float* __restrict__ pw,
    const float* __restrict__ gw, const float* __restrict__ ww,
    short* __restrict__ Wf)
{
    int gid  = blockIdx.x * 256 + threadIdx.x;   // 32768 threads
    int lane = gid & 63;
    int grp  = gid >> 6;                          // [0,512): m*128 + ot*8 + ks
    int ks = grp & 7, ot = (grp >> 3) & 15, m = grp >> 7;
    const float* W = (m == 0) ? tw : (m == 1) ? pw : (m == 2) ? gw : ww;
    const float* p = &W[(size_t)(ot * 16 + (lane & 15)) * 256 + ks * 32 + (lane >> 4) * 8];
    float4 a = *(const float4*)p, c = *(const float4*)(p + 4);
    s16x8 o;
    o[0] = f2bf(a.x); o[1] = f2bf(a.y); o[2] = f2bf(a.z); o[3] = f2bf(a.w);
    o[4] = f2bf(c.x); o[5] = f2bf(c.y); o[6] = f2bf(c.z); o[7] = f2bf(c.w);
    *(s16x8*)&Wf[(size_t)gid * 8] = o;
}

// ---------------------------------------------------------------------------
// Kernel 1: projections — MERGED: one block per (b, n0) computes all 3
// matrices (x staged ONCE, bfr frags computed once, 3x MFMA per staging).
//   m=0 theta -> Qf fragment-packed, scaled by log2e (incl. bias)
//   m=1 phi   -> Kf fragment-packed (same layout)
//   m=2 g     -> Vf fragment-packed: Vf[b][t][i(16)][L(64)][8]
// ---------------------------------------------------------------------------
__global__ __launch_bounds__(256) void proj_kernel(
    const float* __restrict__ x, const short* __restrict__ Wf,
    const float* __restrict__ tb, const float* __restrict__ pb,
    const float* __restrict__ gb,
    short* __restrict__ Qf, short* __restrict__ Kf, short* __restrict__ Vf)
{
    __shared__ char xls[64 * 512];   // xT tile [n(64)][c(256)] bf16, XOR-swizzled
    const int blk = blockIdx.x;            // 256 blocks = B * N/64
    const int b   = blk >> 7;
    const int n0  = (blk & 127) << 6;
    const int tid = threadIdx.x;

    for (int it = 0; it < 16; ++it) {
        int chunk = it * 256 + tid;
        int c  = chunk >> 4;
        int n4 = (chunk & 15) << 2;
        const float4 v = *(const float4*)&x[((size_t)b * CC + c) * NN + n0 + n4];
        float vv[4] = {v.x, v.y, v.z, v.w};
        #pragma unroll
        for (int j = 0; j < 4; ++j) {
            int row = n4 + j;
            int addr = row * 512 + ((c * 2) ^ ((row & 31) << 4));
            *(short*)(xls + addr) = f2bf(vv[j]);
        }
    }
    __syncthreads();

    const int lane = tid & 63, w = tid >> 6;
    const int lo = lane & 15, g = lane >> 4;

    s16x8 bfr[8];
    #pragma unroll
    for (int k = 0; k < 8; ++k) {
        int row = w * 16 + lo;
        int addr = row * 512 + ((k * 64 + g * 16) ^ ((row & 31) << 4));
        bfr[k] = *(const s16x8*)(xls + addr);
    }

    for (int m = 0; m < 3; ++m) {
        const float* bias = (m == 0) ? tb : (m == 1) ? pb : gb;
        const size_t wfm = (size_t)m * 16 * 8 * 512;

        for (int ot = 0; ot < 16; ++ot) {
            s16x8 afr[8];
            #pragma unroll
            for (int k = 0; k < 8; ++k)
                afr[k] = *(const s16x8*)&Wf[wfm + (size_t)(ot * 8 + k) * 512 + lane * 8];
            f32x4 acc = {0.f, 0.f, 0.f, 0.f};
            if (m < 2) {
                #pragma unroll
                for (int k = 0; k < 8; ++k)
                    acc = __builtin_amdgcn_mfma_f32_16x16x32_bf16(afr[k], bfr[k], acc, 0, 0, 0);
            } else {
                #pragma unroll
                for (int k = 0; k < 8; ++k)
                    acc = __builtin_amdgcn_mfma_f32_16x16x32_bf16(bfr[k], afr[k], acc, 0, 0, 0);
            }

            if (m < 2) {
                // lane holds out[c=ot*16+g*4+r][n=n0+w*16+lo] -> packed frag layout
                const float4 bi = *(const float4*)&bias[ot * 16 + g * 4];
                const float sc = (m == 0) ? LOG2E : 1.0f;
                short* O = (m == 0) ? Qf : Kf;
                int n = n0 + w * 16 + lo;
                s16x4 st;
                st[0] = f2bf((acc[0] + bi.x) * sc);
                st[1] = f2bf((acc[1] + bi.y) * sc);
                st[2] = f2bf((acc[2] + bi.z) * sc);
                st[3] = f2bf((acc[3] + bi.w) * sc);
                size_t a = ((((size_t)b * 256 + (n >> 5)) * 16 + ot) * 64
                            + (n & 31) + 32 * (g >> 1)) * 8 + (g & 1) * 4;
                *(s16x4*)&O[a] = st;
            } else {
                int nb = n0 + w * 16 + g * 4;
                int o  = ot * 16 + lo;
                float bo = bias[o];
                s16x4 st;
                st[0] = f2bf(acc[0] + bo);
                st[1] = f2bf(acc[1] + bo);
                st[2] = f2bf(acc[2] + bo);
                st[3] = f2bf(acc[3] + bo);
                size_t a = ((((size_t)b * 256 + (nb >> 5)) * 16 + (w & 1) * 8 + (ot >> 1)) * 64
                            + (ot & 1) * 16 + lo + 32 * (g >> 1)) * 8 + (g & 1) * 4;
                *(s16x4*)&Vf[a] = st;
            }
        }
    }
}

// ---------------------------------------------------------------------------
// Kernel 2: flash attention (FROZEN round-10 structure, best measured).
//   wave = 32 q rows, 4-wave blocks, launch_bounds(256,2) -> 2 waves/SIMD.
//   Fixed-max softmax, P = 2^s, l reduced once in epilogue.
//   K,V double-buffered LDS (2x32KB), coalesced gload16 from packed Kf/Vf.
//   part layout: part_p[s][b][qb(256)][slot=dt*4+rg][lane][4e]
// ---------------------------------------------------------------------------
template<int SPLIT>
__global__ __launch_bounds__(256, 2) void attn6_kernel(
    const short* __restrict__ Qf, const short* __restrict__ Kf,
    const short* __restrict__ Vf,
    short* __restrict__ part,    // packed, unnormalized
    float* __restrict__ ml)      // [SPLIT][B*N][2]  (0, l)
{
    __shared__ char lds[65536];  // 2 bufs x (K 16KB | V 16KB)
    const int blk   = blockIdx.x;
    const int combo = blk & (2 * SPLIT - 1);      // XCD-affine grouping
    const int split = combo >> 1;
    const int b     = combo & 1;
    const int qblk  = blk / (2 * SPLIT);          // 0..63
    const int tid = threadIdx.x, lane = tid & 63, w = tid >> 6;
    const int l31 = lane & 31, h = lane >> 5;
    const size_t bN = (size_t)b * NN;
    const int tgbase = (split * (NN / SPLIT)) >> 5;
    const int NT = (NN / SPLIT) / 32;

    // ---- stage tile 0 (K: insts 0-15, V: insts 16-31; each wave issues 8)
    #pragma unroll
    for (int j = 0; j < 8; ++j) {
        const int inst = w * 8 + j;
        if (inst < 16)
            gload16(&Kf[(((size_t)(b * 256 + tgbase) * 16) + inst) * 512 + lane * 8],
                    lds + inst * 1024);
        else
            gload16(&Vf[(((size_t)(b * 256 + tgbase) * 16) + (inst - 16)) * 512 + lane * 8],
                    lds + 16384 + (inst - 16) * 1024);
    }

    // ---- Q fragments (coalesced from packed Qf): this wave's 32 q rows
    s16x8 qf[16];
    {
        const int qtg = qblk * 4 + w;
        #pragma unroll
        for (int ks = 0; ks < 16; ++ks)
            qf[ks] = *(const s16x8*)&Qf[(((size_t)(b * 256 + qtg) * 16) + ks) * 512 + lane * 8];
    }

    f32x16 acc[8];
    #pragma unroll
    for (int dt = 0; dt < 8; ++dt)
        #pragma unroll
        for (int r = 0; r < 16; ++r) acc[dt][r] = 0.f;
    float l_run = 0.f;   // per-half partial; reduced in epilogue

    for (int t = 0; t < NT; ++t) {
        __syncthreads();   // tile t staged
        const char* cbuf = lds + (t & 1) * 32768;
        const int tg = tgbase + t;
        if (t + 1 < NT) {
            char* nbuf = lds + ((t + 1) & 1) * 32768;
            #pragma unroll
            for (int j = 0; j < 8; ++j) {
                const int inst = w * 8 + j;
                if (inst < 16)
                    gload16(&Kf[(((size_t)(b * 256 + tg + 1) * 16) + inst) * 512 + lane * 8],
                            nbuf + inst * 1024);
                else
                    gload16(&Vf[(((size_t)(b * 256 + tg + 1) * 16) + (inst - 16)) * 512 + lane * 8],
                            nbuf + 16384 + (inst - 16) * 1024);
            }
        }

        // ---- QK^T: S[kv=32][q=32]; lane: q=l31, kv(reg)=(reg&3)+8*(reg>>2)+4h
        f32x16 sacc;
        #pragma unroll
        for (int r = 0; r < 16; ++r) sacc[r] = 0.f;
        __builtin_amdgcn_s_setprio(1);
        #pragma unroll
        for (int ks = 0; ks < 16; ++ks) {
            s16x8 kf = *(const s16x8*)(cbuf + ks * 1024 + lane * 16);
            sacc = __builtin_amdgcn_mfma_f32_32x32x16_bf16(kf, qf[ks], sacc, 0, 0, 0);
        }
        __builtin_amdgcn_s_setprio(0);

        // ---- fixed-max softmax: P = 2^s (Q pre-scaled by log2e)
        float sum = 0.f;
        #pragma unroll
        for (int r = 0; r < 16; ++r) {
            float p = exp2f(sacc[r]);
            sacc[r] = p; sum += p;
        }
        l_run += sum;

        // ---- P -> bf16 B-frags, slot k = h*8+e.
        // permlane32_swap(a,b): ret[0]=[a_lo|b_lo], ret[1]=[a_hi|b_hi]
        union { int wd[4]; s16x8 v; } f0, f1;
        {
            int w01, w23, w45, w67;
            asm("v_cvt_pk_bf16_f32 %0, %1, %2" : "=v"(w01) : "v"(sacc[0]), "v"(sacc[1]));
            asm("v_cvt_pk_bf16_f32 %0, %1, %2" : "=v"(w23) : "v"(sacc[2]), "v"(sacc[3]));
            asm("v_cvt_pk_bf16_f32 %0, %1, %2" : "=v"(w45) : "v"(sacc[4]), "v"(sacc[5]));
            asm("v_cvt_pk_bf16_f32 %0, %1, %2" : "=v"(w67) : "v"(sacc[6]), "v"(sacc[7]));
            i32x2 r02 = __builtin_amdgcn_permlane32_swap(w01, w45, false, false);
            i32x2 r13 = __builtin_amdgcn_permlane32_swap(w23, w67, false, false);
            f0.wd[0] = r02[0]; f0.wd[1] = r13[0];
            f0.wd[2] = r02[1]; f0.wd[3] = r13[1];
        }
        {
            int w01, w23, w45, w67;
            asm("v_cvt_pk_bf16_f32 %0, %1, %2" : "=v"(w01) : "v"(sacc[8]),  "v"(sacc[9]));
            asm("v_cvt_pk_bf16_f32 %0, %1, %2" : "=v"(w23) : "v"(sacc[10]), "v"(sacc[11]));
            asm("v_cvt_pk_bf16_f32 %0, %1, %2" : "=v"(w45) : "v"(sacc[12]), "v"(sacc[13]));
            asm("v_cvt_pk_bf16_f32 %0, %1, %2" : "=v"(w67) : "v"(sacc[14]), "v"(sacc[15]));
            i32x2 r02 = __builtin_amdgcn_permlane32_swap(w01, w45, false, false);
            i32x2 r13 = __builtin_amdgcn_permlane32_swap(w23, w67, false, false);
            f1.wd[0] = r02[0]; f1.wd[1] = r13[0];
            f1.wd[2] = r02[1]; f1.wd[3] = r13[1];
        }

        // ---- PV: O^T[d][q] += V^T-frag x P-frag (V from LDS)
        const char* vbuf = cbuf + 16384;
        __builtin_amdgcn_s_setprio(1);
        #pragma unroll
        for (int dt = 0; dt < 8; ++dt) {
            s16x8 v0 = *(const s16x8*)(vbuf + (dt) * 1024 + lane * 16);
            s16x8 v1 = *(const s16x8*)(vbuf + (8 + dt) * 1024 + lane * 16);
            acc[dt] = __builtin_amdgcn_mfma_f32_32x32x16_bf16(v0, f0.v, acc[dt], 0, 0, 0);
            acc[dt] = __builtin_amdgcn_mfma_f32_32x32x16_bf16(v1, f1.v, acc[dt], 0, 0, 0);
        }
        __builtin_amdgcn_s_setprio(0);
    }

    // ---- epilogue: packed unnormalized partial + (0, l)
    const int qb = qblk * 4 + w;
    const size_t pb2 = (((size_t)(split * 2 + b) * 256 + qb) * 32) * 256;
    #pragma unroll
    for (int dt = 0; dt < 8; ++dt)
        #pragma unroll
        for (int rg = 0; rg < 4; ++rg) {
            s16x4 st;
            st[0] = f2bf(acc[dt][rg * 4 + 0]);
            st[1] = f2bf(acc[dt][rg * 4 + 1]);
            st[2] = f2bf(acc[dt][rg * 4 + 2]);
            st[3] = f2bf(acc[dt][rg * 4 + 3]);
            *(s16x4*)&part[pb2 + (size_t)(dt * 4 + rg) * 256 + lane * 4] = st;
        }
    float lf = l_run + __shfl_xor(l_run, 32);
    if (h == 0) {
        size_t mi = ((size_t)split * (BB * NN) + bN + qb * 32 + l31) * 2;
        ml[mi] = 0.f; ml[mi + 1] = lf;
    }
}

// ---------------------------------------------------------------------------
// Kernel 3 (legacy, small-ws path): combine packed partials -> yp
// ---------------------------------------------------------------------------
template<int SPLIT>
__global__ __launch_bounds__(256) void combine2_kernel(
    const short* __restrict__ part, const float* __restrict__ ml,
    short* __restrict__ yp)
{
    int gid  = blockIdx.x * 256 + threadIdx.x;
    int lane = gid & 63;
    int slot = (gid >> 6) & 31;
    int qb   = (gid >> 11) & 255;
    int b    = gid >> 19;
    int dt = slot >> 2, rg = slot & 3;
    int l31 = lane & 31, h = lane >> 5;
    int q = qb * 32 + l31;

    float mm[SPLIT], ll[SPLIT];
    float m = -1e30f;
    #pragma unroll
    for (int s = 0; s < SPLIT; ++s) {
        mm[s] = ml[((size_t)s * (BB * NN) + (size_t)b * NN + q) * 2];
        ll[s] = ml[((size_t)s * (BB * NN) + (size_t)b * NN + q) * 2 + 1];
        m = fmaxf(m, mm[s]);
    }
    float den = 0.f, a[SPLIT];
    #pragma unroll
    for (int s = 0; s < SPLIT; ++s) { a[s] = __expf(mm[s] - m); den += a[s] * ll[s]; }
    float o[4] = {0.f, 0.f, 0.f, 0.f};
    #pragma unroll
    for (int s = 0; s < SPLIT; ++s) {
        s16x4 p = *(const s16x4*)&part[((((size_t)(s * 2 + b) * 256 + qb) * 32 + slot) * 64 + lane) * 4];
        #pragma unroll
        for (int j = 0; j < 4; ++j) o[j] += a[s] * bf2f(p[j]);
    }
    float inv = 1.f / den;
    s16x4 st;
    #pragma unroll
    for (int j = 0; j < 4; ++j) st[j] = f2bf(o[j] * inv);
    size_t a2 = ((((size_t)b * 512 + (q >> 4)) * 8 + dt) * 64 + (q & 15) + rg * 16) * 8 + h * 4;
    *(s16x4*)&yp[a2] = st;
}

// ---------------------------------------------------------------------------
// Kernel 4a (big path): z = W*y + b from part+ml (combine fused) AND emit
// per-block BN partial sums: bnp[o][blk] = (sum z, sum z^2 over 64 n-cols).
// ---------------------------------------------------------------------------
template<int SPLIT>
__global__ __launch_bounds__(256) void zgemm_fused_kernel(
    const short* __restrict__ part, const float* __restrict__ ml,
    const short* __restrict__ Wf, const float* __restrict__ wb,
    float* __restrict__ z, float* __restrict__ bnpart)
{
    __shared__ float bnp[4][256][2];   // [wave][channel][sum,sumsq]
    const int blk = blockIdx.x;
    const int b   = blk >> 7;
    const int n0  = (blk & 127) << 6;
    const int tid = threadIdx.x;
    const int lane = tid & 63, w = tid >> 6, lo = lane & 15, g = lane >> 4;
    const int q  = n0 + w * 16 + lo;
    const int qb = q >> 5, l31 = q & 31;

    float mm[SPLIT], ll[SPLIT], a[SPLIT];
    float m = -1e30f;
    #pragma unroll
    for (int s = 0; s < SPLIT; ++s) {
        mm[s] = ml[((size_t)s * (BB * NN) + (size_t)b * NN + q) * 2];
        ll[s] = ml[((size_t)s * (BB * NN) + (size_t)b * NN + q) * 2 + 1];
        m = fmaxf(m, mm[s]);
    }
    float den = 0.f;
    #pragma unroll
    for (int s = 0; s < SPLIT; ++s) { a[s] = __expf(mm[s] - m); den += a[s] * ll[s]; }
    float inv = 1.f / den;
    #pragma unroll
    for (int s = 0; s < SPLIT; ++s) a[s] *= inv;

    // A-frags: afr[k][e] = y[q][k*32 + g*8 + e], normalized from partials
    s16x8 afr[8];
    #pragma unroll
    for (int k = 0; k < 8; ++k) {
        float o[8] = {0.f, 0.f, 0.f, 0.f, 0.f, 0.f, 0.f, 0.f};
        #pragma unroll
        for (int s = 0; s < SPLIT; ++s) {
            size_t base = ((((size_t)(s * 2 + b) * 256 + qb) * 32 + (k * 4 + g)) * 64 + l31) * 4;
            s16x4 plo = *(const s16x4*)&part[base];
            s16x4 phi = *(const s16x4*)&part[base + 128];
            #pragma unroll
            for (int j = 0; j < 4; ++j) {
                o[j]     += a[s] * bf2f(plo[j]);
                o[4 + j] += a[s] * bf2f(phi[j]);
            }
        }
        #pragma unroll
        for (int j = 0; j < 8; ++j) afr[k][j] = f2bf(o[j]);
    }

    for (int ot = 0; ot < 16; ++ot) {
        f32x4 acc = {0.f, 0.f, 0.f, 0.f};
        #pragma unroll
        for (int k = 0; k < 8; ++k) {
            s16x8 bfr = *(const s16x8*)&Wf[(size_t)((3 * 16 + ot) * 8 + k) * 512 + lane * 8];
            acc = __builtin_amdgcn_mfma_f32_16x16x32_bf16(afr[k], bfr, acc, 0, 0, 0);
        }
        float bias = wb[ot * 16 + lo];
        float4 st = {acc[0] + bias, acc[1] + bias, acc[2] + bias, acc[3] + bias};
        *(float4*)&z[((size_t)b * CIc + ot * 16 + lo) * NN + n0 + w * 16 + g * 4] = st;

        // per-channel partial stats (channel o = ot*16 + lo; reduce over g)
        float s1 = st.x + st.y + st.z + st.w;
        float s2 = st.x * st.x + st.y * st.y + st.z * st.z + st.w * st.w;
        s1 += __shfl_xor(s1, 16); s2 += __shfl_xor(s2, 16);
        s1 += __shfl_xor(s1, 32); s2 += __shfl_xor(s2, 32);
        if (g == 0) { bnp[w][ot * 16 + lo][0] = s1; bnp[w][ot * 16 + lo][1] = s2; }
    }
    __syncthreads();
    // tid = channel: sum 4 waves, write bnpart[o][blk][2]
    float S1 = bnp[0][tid][0] + bnp[1][tid][0] + bnp[2][tid][0] + bnp[3][tid][0];
    float S2 = bnp[0][tid][1] + bnp[1][tid][1] + bnp[2][tid][1] + bnp[3][tid][1];
    bnpart[((size_t)tid * 256 + blk) * 2]     = S1;
    bnpart[((size_t)tid * 256 + blk) * 2 + 1] = S2;
}

// ---------------------------------------------------------------------------
// Kernel 4b (legacy, small-ws path): z = W*y + b from packed yp
// ---------------------------------------------------------------------------
__global__ __launch_bounds__(256) void zgemm_kernel(
    const short* __restrict__ yp, const short* __restrict__ Wf,
    const float* __restrict__ wb, float* __restrict__ z)
{
    const int blk = blockIdx.x;
    const int b   = blk >> 7;
    const int n0  = (blk & 127) << 6;
    const int tid = threadIdx.x;
    const int lane = tid & 63, w = tid >> 6, lo = lane & 15, g = lane >> 4;

    s16x8 afr[8];
    #pragma unroll
    for (int k = 0; k < 8; ++k)
        afr[k] = *(const s16x8*)&yp[((((size_t)b * 512 + (n0 >> 4) + w) * 8 + k) * 64 + lane) * 8];

    for (int ot = 0; ot < 16; ++ot) {
        f32x4 acc = {0.f, 0.f, 0.f, 0.f};
        #pragma unroll
        for (int k = 0; k < 8; ++k) {
            s16x8 bfr = *(const s16x8*)&Wf[(size_t)((3 * 16 + ot) * 8 + k) * 512 + lane * 8];
            acc = __builtin_amdgcn_mfma_f32_16x16x32_bf16(afr[k], bfr, acc, 0, 0, 0);
        }
        float bias = wb[ot * 16 + lo];
        float4 st = {acc[0] + bias, acc[1] + bias, acc[2] + bias, acc[3] + bias};
        *(float4*)&z[((size_t)b * CIc + ot * 16 + lo) * NN + n0 + w * 16 + g * 4] = st;
    }
}

// ---------------------------------------------------------------------------
// Kernel 5a (big path): BN apply from precomputed partials (no stats re-read)
// ---------------------------------------------------------------------------
__global__ __launch_bounds__(256) void bn_apply_kernel(
    float* __restrict__ z, const float* __restrict__ bnpart,
    const float* __restrict__ gamma, const float* __restrict__ beta)
{
    const int o = blockIdx.x;
    const int tid = threadIdx.x;
    float s  = bnpart[((size_t)o * 256 + tid) * 2];
    float s2 = bnpart[((size_t)o * 256 + tid) * 2 + 1];
    #pragma unroll
    for (int off = 1; off < 64; off <<= 1) {
        s  += __shfl_xor(s, off);
        s2 += __shfl_xor(s2, off);
    }
    __shared__ float rs[8];
    if ((tid & 63) == 0) { rs[tid >> 6] = s; rs[4 + (tid >> 6)] = s2; }
    __syncthreads();
    float S  = rs[0] + rs[1] + rs[2] + rs[3];
    float S2 = rs[4] + rs[5] + rs[6] + rs[7];
    float mean = S / (float)(BB * NN);
    float var  = S2 / (float)(BB * NN) - mean * mean;
    float rsq  = rsqrtf(var + 1e-5f);
    float ga = gamma[o], be = beta[o];
    float sc = rsq * ga, of = be - mean * rsq * ga;
    #pragma unroll
    for (int b2 = 0; b2 < BB; ++b2) {
        float* row = &z[((size_t)b2 * CIc + o) * NN];
        #pragma unroll
        for (int i = 0; i < 8; ++i) {
            float4 t = *(const float4*)&row[(i * 256 + tid) * 4];
            t.x = t.x * sc + of;
            t.y = t.y * sc + of;
            t.z = t.z * sc + of;
            t.w = t.w * sc + of;
            *(float4*)&row[(i * 256 + tid) * 4] = t;
        }
    }
}

// ---------------------------------------------------------------------------
// Kernel 5b (small-ws path): fused BN (stats + apply), register-cached
// ---------------------------------------------------------------------------
__global__ __launch_bounds__(256) void bn_kernel(
    float* __restrict__ z,
    const float* __restrict__ gamma, const float* __restrict__ beta)
{
    const int o = blockIdx.x;
    const int tid = threadIdx.x;
    float4 v[16];
    float s = 0.f, s2 = 0.f;
    #pragma unroll
    for (int b2 = 0; b2 < BB; ++b2) {
        float* row = &z[((size_t)b2 * CIc + o) * NN];
        #pragma unroll
        for (int i = 0; i < 8; ++i) {
            float4 t = *(const float4*)&row[(i * 256 + tid) * 4];
            v[b2 * 8 + i] = t;
            s  += t.x + t.y + t.z + t.w;
            s2 += t.x * t.x + t.y * t.y + t.z * t.z + t.w * t.w;
        }
    }
    #pragma unroll
    for (int off = 1; off < 64; off <<= 1) {
        s  += __shfl_xor(s, off);
        s2 += __shfl_xor(s2, off);
    }
    __shared__ float rs[8];
    if ((tid & 63) == 0) { rs[tid >> 6] = s; rs[4 + (tid >> 6)] = s2; }
    __syncthreads();
    float S  = rs[0] + rs[1] + rs[2] + rs[3];
    float S2 = rs[4] + rs[5] + rs[6] + rs[7];
    float mean = S / (float)(BB * NN);
    float var  = S2 / (float)(BB * NN) - mean * mean;
    float rsq  = rsqrtf(var + 1e-5f);
    float ga = gamma[o], be = beta[o];
    float sc = rsq * ga, of = be - mean * rsq * ga;
    #pragma unroll
    for (int b2 = 0; b2 < BB; ++b2) {
        float* row = &z[((size_t)b2 * CIc + o) * NN];
        #pragma unroll
        for (int i = 0; i < 8; ++i) {
            float4 t = v[b2 * 8 + i];
            t.x = t.x * sc + of;
            t.y = t.y * sc + of;
            t.z = t.z * sc + of;
            t.w = t.w * sc + of;
            *(float4*)&row[(i * 256 + tid) * 4] = t;
        }
    }
}

// ---------------------------------------------------------------------------
extern "C" void kernel_launch(void* const* d_in, const int* in_sizes, int n_in,
                              void* d_out, int out_size, void* d_ws, size_t ws_size,
                              hipStream_t stream) {
    const float* x    = (const float*)d_in[0];
    const float* g_w  = (const float*)d_in[1];
    const float* g_b  = (const float*)d_in[2];
    const float* th_w = (const float*)d_in[3];
    const float* th_b = (const float*)d_in[4];
    const float* ph_w = (const float*)d_in[5];
    const float* ph_b = (const float*)d_in[6];
    const float* w_w  = (const float*)d_in[7];
    const float* w_b  = (const float*)d_in[8];
    const float* bn_g = (const float*)d_in[9];
    const float* bn_b = (const float*)d_in[10];

    char* ws = (char*)d_ws;
    short* Qf    = (short*)ws;                         // 8 MiB (reused as yp)
    short* Kf    = (short*)(ws + 8  * 1048576);        // 8 MiB
    short* Vf    = (short*)(ws + 16 * 1048576);        // 8 MiB
    float* ml    = (float*)(ws + 24 * 1048576);        // <= 512 KiB
    short* Wfb   = (short*)(ws + 25 * 1048576);        // 512 KiB
    float* bnp   = (float*)(ws + 25 * 1048576 + 524288);  // 512 KiB
    float* z     = (float*)d_out;

    const size_t need4 = (size_t)26 * 1048576 + (size_t)4 * BB * NN * CIc * 2;
    const bool  big    = ws_size >= need4;

    pack_kernel<<<128, 256, 0, stream>>>(th_w, ph_w, g_w, w_w, Wfb);
    proj_kernel<<<256, 256, 0, stream>>>(x, Wfb, th_b, ph_b, g_b, Qf, Kf, Vf);

    if (big) {
        short* part = (short*)(ws + 26 * 1048576);     // 32 MiB
        attn6_kernel<4><<<512, 256, 0, stream>>>(Qf, Kf, Vf, part, ml);
        zgemm_fused_kernel<4><<<256, 256, 0, stream>>>(part, ml, Wfb, w_b, z, bnp);
        bn_apply_kernel<<<256, 256, 0, stream>>>(z, bnp, bn_g, bn_b);
    } else {
        short* part = (short*)d_out;                   // 2 splits fit d_out exactly
        attn6_kernel<2><<<256, 256, 0, stream>>>(Qf, Kf, Vf, part, ml);
        combine2_kernel<2><<<4096, 256, 0, stream>>>(part, ml, Qf);
        zgemm_kernel<<<256, 256, 0, stream>>>(Qf, Wfb, w_b, z);
        bn_kernel<<<256, 256, 0, stream>>>(z, bn_g, bn_b);
    }
}

// Round 14
// 201.545 us; speedup vs baseline: 1.1220x; 1.1220x over previous
//
#include <hip/hip_runtime.h>
#include <hip/hip_bf16.h>
#include <stdint.h>

// Problem constants
#define BB  2
#define CC  256
#define NN  8192
#define CIc 256
#define LOG2E 1.4426950408889634f

typedef __attribute__((ext_vector_type(4)))  float f32x4;
typedef __attribute__((ext_vector_type(16))) float f32x16;
typedef __attribute__((ext_vector_type(8)))  short s16x8;   // 8 bf16 = 4 VGPR
typedef __attribute__((ext_vector_type(4)))  short s16x4;
typedef __attribute__((ext_vector_type(4)))  int   i32x4;
typedef __attribute__((ext_vector_type(2)))  int   i32x2;

static __device__ __forceinline__ short f2bf(float f) {
    union { float f; unsigned u; } v; v.f = f;
    unsigned r = (v.u + 0x7FFFu + ((v.u >> 16) & 1u)) >> 16;   // RNE
    return (short)r;
}
static __device__ __forceinline__ float bf2f(short h) {
    union { unsigned u; float f; } v; v.u = ((unsigned)(unsigned short)h) << 16;
    return v.f;
}

// async global->LDS, 16B per lane, dest = lds_base + lane*16 (wave-uniform base)
static __device__ __forceinline__ void gload16(const void* g, void* l) {
    __builtin_amdgcn_global_load_lds(
        (const __attribute__((address_space(1))) unsigned int*)g,
        (__attribute__((address_space(3))) unsigned int*)l, 16, 0, 0);
}

// ---------------------------------------------------------------------------
// Kernel 0: pack the 4 weight matrices (theta, phi, g, w) f32[256][256] into
// bf16 MFMA-fragment order:  Wf[m][ot][ks][lane][8e] =
//   W[ot*16 + (lane&15)][ks*32 + (lane>>4)*8 + e]
// ---------------------------------------------------------------------------
__global__ __launch_bounds__(256) void pack_kernel(
    const float* __restrict__ tw, const float* __restrict__ pw,
    const float* __restrict__ gw, const float* __restrict__ ww,
    short* __restrict__ Wf)
{
    int gid  = blockIdx.x * 256 + threadIdx.x;   // 32768 threads
    int lane = gid & 63;
    int grp  = gid >> 6;                          // [0,512): m*128 + ot*8 + ks
    int ks = grp & 7, ot = (grp >> 3) & 15, m = grp >> 7;
    const float* W = (m == 0) ? tw : (m == 1) ? pw : (m == 2) ? gw : ww;
    const float* p = &W[(size_t)(ot * 16 + (lane & 15)) * 256 + ks * 32 + (lane >> 4) * 8];
    float4 a = *(const float4*)p, c = *(const float4*)(p + 4);
    s16x8 o;
    o[0] = f2bf(a.x); o[1] = f2bf(a.y); o[2] = f2bf(a.z); o[3] = f2bf(a.w);
    o[4] = f2bf(c.x); o[5] = f2bf(c.y); o[6] = f2bf(c.z); o[7] = f2bf(c.w);
    *(s16x8*)&Wf[(size_t)gid * 8] = o;
}

// ---------------------------------------------------------------------------
// Kernel 1: projections.  grid = 3 (matrix) x B x N/64.  One matrix per block
// (768 blocks = 3 blocks/CU; more TLP beats staging reuse — round-13 lesson).
//   m=0 theta -> Qf fragment-packed, SCALED BY log2(e) (incl. bias) so attn
//                can use exp2 directly.  Qf[b][t][ks(16)][L(64)][8]
//   m=1 phi   -> Kf fragment-packed (same layout, unscaled)
//   m=2 g     -> Vf fragment-packed: Vf[b][t][i(16)][L(64)][8]
// ---------------------------------------------------------------------------
__global__ __launch_bounds__(256) void proj_kernel(
    const float* __restrict__ x, const short* __restrict__ Wf,
    const float* __restrict__ tb, const float* __restrict__ pb,
    const float* __restrict__ gb,
    short* __restrict__ Qf, short* __restrict__ Kf, short* __restrict__ Vf)
{
    __shared__ char xls[64 * 512];   // xT tile [n(64)][c(256)] bf16, XOR-swizzled
    const int blk = blockIdx.x;            // 768 blocks
    const int m   = blk % 3;
    const int r2  = blk / 3;
    const int b   = r2 >> 7;
    const int n0  = (r2 & 127) << 6;
    const int tid = threadIdx.x;

    for (int it = 0; it < 16; ++it) {
        int chunk = it * 256 + tid;
        int c  = chunk >> 4;
        int n4 = (chunk & 15) << 2;
        const float4 v = *(const float4*)&x[((size_t)b * CC + c) * NN + n0 + n4];
        float vv[4] = {v.x, v.y, v.z, v.w};
        #pragma unroll
        for (int j = 0; j < 4; ++j) {
            int row = n4 + j;
            int addr = row * 512 + ((c * 2) ^ ((row & 31) << 4));
            *(short*)(xls + addr) = f2bf(vv[j]);
        }
    }
    __syncthreads();

    const int lane = tid & 63, w = tid >> 6;
    const int lo = lane & 15, g = lane >> 4;

    s16x8 bfr[8];
    #pragma unroll
    for (int k = 0; k < 8; ++k) {
        int row = w * 16 + lo;
        int addr = row * 512 + ((k * 64 + g * 16) ^ ((row & 31) << 4));
        bfr[k] = *(const s16x8*)(xls + addr);
    }

    const float* bias = (m == 0) ? tb : (m == 1) ? pb : gb;
    const size_t wfm = (size_t)m * 16 * 8 * 512;

    for (int ot = 0; ot < 16; ++ot) {
        s16x8 afr[8];
        #pragma unroll
        for (int k = 0; k < 8; ++k)
            afr[k] = *(const s16x8*)&Wf[wfm + (size_t)(ot * 8 + k) * 512 + lane * 8];
        f32x4 acc = {0.f, 0.f, 0.f, 0.f};
        if (m < 2) {
            #pragma unroll
            for (int k = 0; k < 8; ++k)
                acc = __builtin_amdgcn_mfma_f32_16x16x32_bf16(afr[k], bfr[k], acc, 0, 0, 0);
        } else {
            #pragma unroll
            for (int k = 0; k < 8; ++k)
                acc = __builtin_amdgcn_mfma_f32_16x16x32_bf16(bfr[k], afr[k], acc, 0, 0, 0);
        }

        if (m < 2) {
            // lane holds out[c=ot*16+g*4+r][n=n0+w*16+lo] -> packed frag layout
            const float4 bi = *(const float4*)&bias[ot * 16 + g * 4];
            const float sc = (m == 0) ? LOG2E : 1.0f;
            short* O = (m == 0) ? Qf : Kf;
            int n = n0 + w * 16 + lo;
            s16x4 st;
            st[0] = f2bf((acc[0] + bi.x) * sc);
            st[1] = f2bf((acc[1] + bi.y) * sc);
            st[2] = f2bf((acc[2] + bi.z) * sc);
            st[3] = f2bf((acc[3] + bi.w) * sc);
            size_t a = ((((size_t)b * 256 + (n >> 5)) * 16 + ot) * 64
                        + (n & 31) + 32 * (g >> 1)) * 8 + (g & 1) * 4;
            *(s16x4*)&O[a] = st;
        } else {
            int nb = n0 + w * 16 + g * 4;
            int o  = ot * 16 + lo;
            float bo = bias[o];
            s16x4 st;
            st[0] = f2bf(acc[0] + bo);
            st[1] = f2bf(acc[1] + bo);
            st[2] = f2bf(acc[2] + bo);
            st[3] = f2bf(acc[3] + bo);
            size_t a = ((((size_t)b * 256 + (nb >> 5)) * 16 + (w & 1) * 8 + (ot >> 1)) * 64
                        + (ot & 1) * 16 + lo + 32 * (g >> 1)) * 8 + (g & 1) * 4;
            *(s16x4*)&Vf[a] = st;
        }
    }
}

// ---------------------------------------------------------------------------
// Kernel 2: flash attention (FROZEN round-10 structure, best measured).
//   wave = 32 q rows, 4-wave blocks, launch_bounds(256,2) -> 2 waves/SIMD.
//   Fixed-max softmax, P = 2^s, l reduced once in epilogue.
//   K,V double-buffered LDS (2x32KB), coalesced gload16 from packed Kf/Vf.
//   part layout: part_p[s][b][qb(256)][slot=dt*4+rg][lane][4e]
// ---------------------------------------------------------------------------
template<int SPLIT>
__global__ __launch_bounds__(256, 2) void attn6_kernel(
    const short* __restrict__ Qf, const short* __restrict__ Kf,
    const short* __restrict__ Vf,
    short* __restrict__ part,    // packed, unnormalized
    float* __restrict__ ml)      // [SPLIT][B*N][2]  (0, l)
{
    __shared__ char lds[65536];  // 2 bufs x (K 16KB | V 16KB)
    const int blk   = blockIdx.x;
    const int combo = blk & (2 * SPLIT - 1);      // XCD-affine grouping
    const int split = combo >> 1;
    const int b     = combo & 1;
    const int qblk  = blk / (2 * SPLIT);          // 0..63
    const int tid = threadIdx.x, lane = tid & 63, w = tid >> 6;
    const int l31 = lane & 31, h = lane >> 5;
    const size_t bN = (size_t)b * NN;
    const int tgbase = (split * (NN / SPLIT)) >> 5;
    const int NT = (NN / SPLIT) / 32;

    // ---- stage tile 0 (K: insts 0-15, V: insts 16-31; each wave issues 8)
    #pragma unroll
    for (int j = 0; j < 8; ++j) {
        const int inst = w * 8 + j;
        if (inst < 16)
            gload16(&Kf[(((size_t)(b * 256 + tgbase) * 16) + inst) * 512 + lane * 8],
                    lds + inst * 1024);
        else
            gload16(&Vf[(((size_t)(b * 256 + tgbase) * 16) + (inst - 16)) * 512 + lane * 8],
                    lds + 16384 + (inst - 16) * 1024);
    }

    // ---- Q fragments (coalesced from packed Qf): this wave's 32 q rows
    s16x8 qf[16];
    {
        const int qtg = qblk * 4 + w;
        #pragma unroll
        for (int ks = 0; ks < 16; ++ks)
            qf[ks] = *(const s16x8*)&Qf[(((size_t)(b * 256 + qtg) * 16) + ks) * 512 + lane * 8];
    }

    f32x16 acc[8];
    #pragma unroll
    for (int dt = 0; dt < 8; ++dt)
        #pragma unroll
        for (int r = 0; r < 16; ++r) acc[dt][r] = 0.f;
    float l_run = 0.f;   // per-half partial; reduced in epilogue

    for (int t = 0; t < NT; ++t) {
        __syncthreads();   // tile t staged
        const char* cbuf = lds + (t & 1) * 32768;
        const int tg = tgbase + t;
        if (t + 1 < NT) {
            char* nbuf = lds + ((t + 1) & 1) * 32768;
            #pragma unroll
            for (int j = 0; j < 8; ++j) {
                const int inst = w * 8 + j;
                if (inst < 16)
                    gload16(&Kf[(((size_t)(b * 256 + tg + 1) * 16) + inst) * 512 + lane * 8],
                            nbuf + inst * 1024);
                else
                    gload16(&Vf[(((size_t)(b * 256 + tg + 1) * 16) + (inst - 16)) * 512 + lane * 8],
                            nbuf + 16384 + (inst - 16) * 1024);
            }
        }

        // ---- QK^T: S[kv=32][q=32]; lane: q=l31, kv(reg)=(reg&3)+8*(reg>>2)+4h
        f32x16 sacc;
        #pragma unroll
        for (int r = 0; r < 16; ++r) sacc[r] = 0.f;
        __builtin_amdgcn_s_setprio(1);
        #pragma unroll
        for (int ks = 0; ks < 16; ++ks) {
            s16x8 kf = *(const s16x8*)(cbuf + ks * 1024 + lane * 16);
            sacc = __builtin_amdgcn_mfma_f32_32x32x16_bf16(kf, qf[ks], sacc, 0, 0, 0);
        }
        __builtin_amdgcn_s_setprio(0);

        // ---- fixed-max softmax: P = 2^s (Q pre-scaled by log2e)
        float sum = 0.f;
        #pragma unroll
        for (int r = 0; r < 16; ++r) {
            float p = exp2f(sacc[r]);
            sacc[r] = p; sum += p;
        }
        l_run += sum;

        // ---- P -> bf16 B-frags, slot k = h*8+e.
        // permlane32_swap(a,b): ret[0]=[a_lo|b_lo], ret[1]=[a_hi|b_hi]
        union { int wd[4]; s16x8 v; } f0, f1;
        {
            int w01, w23, w45, w67;
            asm("v_cvt_pk_bf16_f32 %0, %1, %2" : "=v"(w01) : "v"(sacc[0]), "v"(sacc[1]));
            asm("v_cvt_pk_bf16_f32 %0, %1, %2" : "=v"(w23) : "v"(sacc[2]), "v"(sacc[3]));
            asm("v_cvt_pk_bf16_f32 %0, %1, %2" : "=v"(w45) : "v"(sacc[4]), "v"(sacc[5]));
            asm("v_cvt_pk_bf16_f32 %0, %1, %2" : "=v"(w67) : "v"(sacc[6]), "v"(sacc[7]));
            i32x2 r02 = __builtin_amdgcn_permlane32_swap(w01, w45, false, false);
            i32x2 r13 = __builtin_amdgcn_permlane32_swap(w23, w67, false, false);
            f0.wd[0] = r02[0]; f0.wd[1] = r13[0];
            f0.wd[2] = r02[1]; f0.wd[3] = r13[1];
        }
        {
            int w01, w23, w45, w67;
            asm("v_cvt_pk_bf16_f32 %0, %1, %2" : "=v"(w01) : "v"(sacc[8]),  "v"(sacc[9]));
            asm("v_cvt_pk_bf16_f32 %0, %1, %2" : "=v"(w23) : "v"(sacc[10]), "v"(sacc[11]));
            asm("v_cvt_pk_bf16_f32 %0, %1, %2" : "=v"(w45) : "v"(sacc[12]), "v"(sacc[13]));
            asm("v_cvt_pk_bf16_f32 %0, %1, %2" : "=v"(w67) : "v"(sacc[14]), "v"(sacc[15]));
            i32x2 r02 = __builtin_amdgcn_permlane32_swap(w01, w45, false, false);
            i32x2 r13 = __builtin_amdgcn_permlane32_swap(w23, w67, false, false);
            f1.wd[0] = r02[0]; f1.wd[1] = r13[0];
            f1.wd[2] = r02[1]; f1.wd[3] = r13[1];
        }

        // ---- PV: O^T[d][q] += V^T-frag x P-frag (V from LDS)
        const char* vbuf = cbuf + 16384;
        __builtin_amdgcn_s_setprio(1);
        #pragma unroll
        for (int dt = 0; dt < 8; ++dt) {
            s16x8 v0 = *(const s16x8*)(vbuf + (dt) * 1024 + lane * 16);
            s16x8 v1 = *(const s16x8*)(vbuf + (8 + dt) * 1024 + lane * 16);
            acc[dt] = __builtin_amdgcn_mfma_f32_32x32x16_bf16(v0, f0.v, acc[dt], 0, 0, 0);
            acc[dt] = __builtin_amdgcn_mfma_f32_32x32x16_bf16(v1, f1.v, acc[dt], 0, 0, 0);
        }
        __builtin_amdgcn_s_setprio(0);
    }

    // ---- epilogue: packed unnormalized partial + (0, l)
    const int qb = qblk * 4 + w;
    const size_t pb2 = (((size_t)(split * 2 + b) * 256 + qb) * 32) * 256;
    #pragma unroll
    for (int dt = 0; dt < 8; ++dt)
        #pragma unroll
        for (int rg = 0; rg < 4; ++rg) {
            s16x4 st;
            st[0] = f2bf(acc[dt][rg * 4 + 0]);
            st[1] = f2bf(acc[dt][rg * 4 + 1]);
            st[2] = f2bf(acc[dt][rg * 4 + 2]);
            st[3] = f2bf(acc[dt][rg * 4 + 3]);
            *(s16x4*)&part[pb2 + (size_t)(dt * 4 + rg) * 256 + lane * 4] = st;
        }
    float lf = l_run + __shfl_xor(l_run, 32);
    if (h == 0) {
        size_t mi = ((size_t)split * (BB * NN) + bN + qb * 32 + l31) * 2;
        ml[mi] = 0.f; ml[mi + 1] = lf;
    }
}

// ---------------------------------------------------------------------------
// Kernel 3 (legacy, small-ws path): combine packed partials -> yp
// ---------------------------------------------------------------------------
template<int SPLIT>
__global__ __launch_bounds__(256) void combine2_kernel(
    const short* __restrict__ part, const float* __restrict__ ml,
    short* __restrict__ yp)
{
    int gid  = blockIdx.x * 256 + threadIdx.x;
    int lane = gid & 63;
    int slot = (gid >> 6) & 31;
    int qb   = (gid >> 11) & 255;
    int b    = gid >> 19;
    int dt = slot >> 2, rg = slot & 3;
    int l31 = lane & 31, h = lane >> 5;
    int q = qb * 32 + l31;

    float mm[SPLIT], ll[SPLIT];
    float m = -1e30f;
    #pragma unroll
    for (int s = 0; s < SPLIT; ++s) {
        mm[s] = ml[((size_t)s * (BB * NN) + (size_t)b * NN + q) * 2];
        ll[s] = ml[((size_t)s * (BB * NN) + (size_t)b * NN + q) * 2 + 1];
        m = fmaxf(m, mm[s]);
    }
    float den = 0.f, a[SPLIT];
    #pragma unroll
    for (int s = 0; s < SPLIT; ++s) { a[s] = __expf(mm[s] - m); den += a[s] * ll[s]; }
    float o[4] = {0.f, 0.f, 0.f, 0.f};
    #pragma unroll
    for (int s = 0; s < SPLIT; ++s) {
        s16x4 p = *(const s16x4*)&part[((((size_t)(s * 2 + b) * 256 + qb) * 32 + slot) * 64 + lane) * 4];
        #pragma unroll
        for (int j = 0; j < 4; ++j) o[j] += a[s] * bf2f(p[j]);
    }
    float inv = 1.f / den;
    s16x4 st;
    #pragma unroll
    for (int j = 0; j < 4; ++j) st[j] = f2bf(o[j] * inv);
    size_t a2 = ((((size_t)b * 512 + (q >> 4)) * 8 + dt) * 64 + (q & 15) + rg * 16) * 8 + h * 4;
    *(s16x4*)&yp[a2] = st;
}

// ---------------------------------------------------------------------------
// Kernel 4a (big path): z = W*y + b, reading part+ml directly (combine fused)
// ---------------------------------------------------------------------------
template<int SPLIT>
__global__ __launch_bounds__(256) void zgemm_fused_kernel(
    const short* __restrict__ part, const float* __restrict__ ml,
    const short* __restrict__ Wf, const float* __restrict__ wb,
    float* __restrict__ z)
{
    const int blk = blockIdx.x;
    const int b   = blk >> 7;
    const int n0  = (blk & 127) << 6;
    const int tid = threadIdx.x;
    const int lane = tid & 63, w = tid >> 6, lo = lane & 15, g = lane >> 4;
    const int q  = n0 + w * 16 + lo;
    const int qb = q >> 5, l31 = q & 31;

    float mm[SPLIT], ll[SPLIT], a[SPLIT];
    float m = -1e30f;
    #pragma unroll
    for (int s = 0; s < SPLIT; ++s) {
        mm[s] = ml[((size_t)s * (BB * NN) + (size_t)b * NN + q) * 2];
        ll[s] = ml[((size_t)s * (BB * NN) + (size_t)b * NN + q) * 2 + 1];
        m = fmaxf(m, mm[s]);
    }
    float den = 0.f;
    #pragma unroll
    for (int s = 0; s < SPLIT; ++s) { a[s] = __expf(mm[s] - m); den += a[s] * ll[s]; }
    float inv = 1.f / den;
    #pragma unroll
    for (int s = 0; s < SPLIT; ++s) a[s] *= inv;

    // A-frags: afr[k][e] = y[q][k*32 + g*8 + e], normalized from partials
    s16x8 afr[8];
    #pragma unroll
    for (int k = 0; k < 8; ++k) {
        float o[8] = {0.f, 0.f, 0.f, 0.f, 0.f, 0.f, 0.f, 0.f};
        #pragma unroll
        for (int s = 0; s < SPLIT; ++s) {
            size_t base = ((((size_t)(s * 2 + b) * 256 + qb) * 32 + (k * 4 + g)) * 64 + l31) * 4;
            s16x4 plo = *(const s16x4*)&part[base];
            s16x4 phi = *(const s16x4*)&part[base + 128];
            #pragma unroll
            for (int j = 0; j < 4; ++j) {
                o[j]     += a[s] * bf2f(plo[j]);
                o[4 + j] += a[s] * bf2f(phi[j]);
            }
        }
        #pragma unroll
        for (int j = 0; j < 8; ++j) afr[k][j] = f2bf(o[j]);
    }

    for (int ot = 0; ot < 16; ++ot) {
        f32x4 acc = {0.f, 0.f, 0.f, 0.f};
        #pragma unroll
        for (int k = 0; k < 8; ++k) {
            s16x8 bfr = *(const s16x8*)&Wf[(size_t)((3 * 16 + ot) * 8 + k) * 512 + lane * 8];
            acc = __builtin_amdgcn_mfma_f32_16x16x32_bf16(afr[k], bfr, acc, 0, 0, 0);
        }
        float bias = wb[ot * 16 + lo];
        float4 st = {acc[0] + bias, acc[1] + bias, acc[2] + bias, acc[3] + bias};
        *(float4*)&z[((size_t)b * CIc + ot * 16 + lo) * NN + n0 + w * 16 + g * 4] = st;
    }
}

// ---------------------------------------------------------------------------
// Kernel 4b (legacy, small-ws path): z = W*y + b from packed yp
// ---------------------------------------------------------------------------
__global__ __launch_bounds__(256) void zgemm_kernel(
    const short* __restrict__ yp, const short* __restrict__ Wf,
    const float* __restrict__ wb, float* __restrict__ z)
{
    const int blk = blockIdx.x;
    const int b   = blk >> 7;
    const int n0  = (blk & 127) << 6;
    const int tid = threadIdx.x;
    const int lane = tid & 63, w = tid >> 6, lo = lane & 15, g = lane >> 4;

    s16x8 afr[8];
    #pragma unroll
    for (int k = 0; k < 8; ++k)
        afr[k] = *(const s16x8*)&yp[((((size_t)b * 512 + (n0 >> 4) + w) * 8 + k) * 64 + lane) * 8];

    for (int ot = 0; ot < 16; ++ot) {
        f32x4 acc = {0.f, 0.f, 0.f, 0.f};
        #pragma unroll
        for (int k = 0; k < 8; ++k) {
            s16x8 bfr = *(const s16x8*)&Wf[(size_t)((3 * 16 + ot) * 8 + k) * 512 + lane * 8];
            acc = __builtin_amdgcn_mfma_f32_16x16x32_bf16(afr[k], bfr, acc, 0, 0, 0);
        }
        float bias = wb[ot * 16 + lo];
        float4 st = {acc[0] + bias, acc[1] + bias, acc[2] + bias, acc[3] + bias};
        *(float4*)&z[((size_t)b * CIc + ot * 16 + lo) * NN + n0 + w * 16 + g * 4] = st;
    }
}

// ---------------------------------------------------------------------------
// Kernel 5: fused BatchNorm (stats + apply), register-cached.
//   One block per channel o.  Each thread holds its 64 elements (16 float4)
//   in registers: one global read, in-register stats, in-register apply,
//   one global write.
// ---------------------------------------------------------------------------
__global__ __launch_bounds__(256) void bn_kernel(
    float* __restrict__ z,
    const float* __restrict__ gamma, const float* __restrict__ beta)
{
    const int o = blockIdx.x;
    const int tid = threadIdx.x;
    float4 v[16];
    float s = 0.f, s2 = 0.f;
    #pragma unroll
    for (int b2 = 0; b2 < BB; ++b2) {
        float* row = &z[((size_t)b2 * CIc + o) * NN];
        #pragma unroll
        for (int i = 0; i < 8; ++i) {
            float4 t = *(const float4*)&row[(i * 256 + tid) * 4];
            v[b2 * 8 + i] = t;
            s  += t.x + t.y + t.z + t.w;
            s2 += t.x * t.x + t.y * t.y + t.z * t.z + t.w * t.w;
        }
    }
    #pragma unroll
    for (int off = 1; off < 64; off <<= 1) {
        s  += __shfl_xor(s, off);
        s2 += __shfl_xor(s2, off);
    }
    __shared__ float rs[8];
    if ((tid & 63) == 0) { rs[tid >> 6] = s; rs[4 + (tid >> 6)] = s2; }
    __syncthreads();
    float S  = rs[0] + rs[1] + rs[2] + rs[3];
    float S2 = rs[4] + rs[5] + rs[6] + rs[7];
    float mean = S / (float)(BB * NN);
    float var  = S2 / (float)(BB * NN) - mean * mean;
    float rsq  = rsqrtf(var + 1e-5f);
    float ga = gamma[o], be = beta[o];
    float sc = rsq * ga, of = be - mean * rsq * ga;
    #pragma unroll
    for (int b2 = 0; b2 < BB; ++b2) {
        float* row = &z[((size_t)b2 * CIc + o) * NN];
        #pragma unroll
        for (int i = 0; i < 8; ++i) {
            float4 t = v[b2 * 8 + i];
            t.x = t.x * sc + of;
            t.y = t.y * sc + of;
            t.z = t.z * sc + of;
            t.w = t.w * sc + of;
            *(float4*)&row[(i * 256 + tid) * 4] = t;
        }
    }
}

// ---------------------------------------------------------------------------
extern "C" void kernel_launch(void* const* d_in, const int* in_sizes, int n_in,
                              void* d_out, int out_size, void* d_ws, size_t ws_size,
                              hipStream_t stream) {
    const float* x    = (const float*)d_in[0];
    const float* g_w  = (const float*)d_in[1];
    const float* g_b  = (const float*)d_in[2];
    const float* th_w = (const float*)d_in[3];
    const float* th_b = (const float*)d_in[4];
    const float* ph_w = (const float*)d_in[5];
    const float* ph_b = (const float*)d_in[6];
    const float* w_w  = (const float*)d_in[7];
    const float* w_b  = (const float*)d_in[8];
    const float* bn_g = (const float*)d_in[9];
    const float* bn_b = (const float*)d_in[10];

    char* ws = (char*)d_ws;
    short* Qf    = (short*)ws;                         // 8 MiB (reused as yp)
    short* Kf    = (short*)(ws + 8  * 1048576);        // 8 MiB
    short* Vf    = (short*)(ws + 16 * 1048576);        // 8 MiB
    float* ml    = (float*)(ws + 24 * 1048576);        // <= 512 KiB
    short* Wfb   = (short*)(ws + 25 * 1048576);        // 512 KiB
    float* z     = (float*)d_out;

    const size_t need4 = (size_t)26 * 1048576 + (size_t)4 * BB * NN * CIc * 2;
    const bool  big    = ws_size >= need4;

    pack_kernel<<<128, 256, 0, stream>>>(th_w, ph_w, g_w, w_w, Wfb);
    proj_kernel<<<768, 256, 0, stream>>>(x, Wfb, th_b, ph_b, g_b, Qf, Kf, Vf);

    if (big) {
        short* part = (short*)(ws + 26 * 1048576);     // 32 MiB
        attn6_kernel<4><<<512, 256, 0, stream>>>(Qf, Kf, Vf, part, ml);
        zgemm_fused_kernel<4><<<256, 256, 0, stream>>>(part, ml, Wfb, w_b, z);
    } else {
        short* part = (short*)d_out;                   // 2 splits fit d_out exactly
        attn6_kernel<2><<<256, 256, 0, stream>>>(Qf, Kf, Vf, part, ml);
        combine2_kernel<2><<<4096, 256, 0, stream>>>(part, ml, Qf);
        zgemm_kernel<<<256, 256, 0, stream>>>(Qf, Wfb, w_b, z);
    }

    bn_kernel<<<256, 256, 0, stream>>>(z, bn_g, bn_b);
}